// Round 1
// baseline (3026.562 us; speedup 1.0000x reference)
//
#include <hip/hip_runtime.h>

static constexpr int H = 4096;
static constexpr int W = 4096;
static constexpr long N = (long)H * W;

__device__ __forceinline__ float4 ld4(const float* p) {
    return *reinterpret_cast<const float4*>(p);
}
__device__ __forceinline__ void st4(float* p, float4 v) {
    *reinterpret_cast<float4*>(p) = v;
}
__device__ __forceinline__ float clamp1(float v) {
    return fminf(fmaxf(v, -1.0f), 1.0f);
}

// Dual update: y = clamp(y + SIGMA * grad(xt) * w, -1, 1)
// Pointwise in y (reads xt halo) -> safe in-place on y.
template<bool FIRST>
__global__ __launch_bounds__(256) void dual_update(
    const float* __restrict__ xt,
    const float* __restrict__ w0,
    const float* __restrict__ w1,
    float* __restrict__ yh,
    float* __restrict__ yv)
{
    const float SIGMA = 14.285714285714286f;  // 1/(7*0.01)
    const int i  = blockIdx.y;
    const int j0 = (blockIdx.x * blockDim.x + threadIdx.x) * 4;
    const long base = (long)i * W + j0;

    float4 c = ld4(xt + base);
    // right neighbor of c.w; if at image edge use c.w so gh = 0 there
    float right = (j0 + 4 < W) ? xt[base + 4] : c.w;
    // row below; if last row use c so gv = 0 there
    float4 below = (i + 1 < H) ? ld4(xt + base + W) : c;

    float4 w0v = ld4(w0 + base);
    float4 w1v = ld4(w1 + base);

    float4 yh_o, yv_o;
    if (FIRST) {
        yh_o = make_float4(0.f, 0.f, 0.f, 0.f);
        yv_o = make_float4(0.f, 0.f, 0.f, 0.f);
    } else {
        yh_o = ld4(yh + base);
        yv_o = ld4(yv + base);
    }

    float4 yh_n, yv_n;
    yh_n.x = clamp1(yh_o.x + SIGMA * (c.y   - c.x) * w0v.x);
    yh_n.y = clamp1(yh_o.y + SIGMA * (c.z   - c.y) * w0v.y);
    yh_n.z = clamp1(yh_o.z + SIGMA * (c.w   - c.z) * w0v.z);
    yh_n.w = clamp1(yh_o.w + SIGMA * (right - c.w) * w0v.w);

    yv_n.x = clamp1(yv_o.x + SIGMA * (below.x - c.x) * w1v.x);
    yv_n.y = clamp1(yv_o.y + SIGMA * (below.y - c.y) * w1v.y);
    yv_n.z = clamp1(yv_o.z + SIGMA * (below.z - c.z) * w1v.z);
    yv_n.w = clamp1(yv_o.w + SIGMA * (below.w - c.w) * w1v.w);

    st4(yh + base, yh_n);
    st4(yv + base, yv_n);
}

// Primal update: x = (x + TAU*div(y) + LT*img) / (1+LT); xt = x + THETA*(x - x_old)
// Reads y halo, writes only own x/xt -> safe in-place on x.
template<bool FIRST>
__global__ __launch_bounds__(256) void primal_update(
    const float* __restrict__ img,
    const float* __restrict__ yh,
    const float* __restrict__ yv,
    const float* __restrict__ x_in,
    float* __restrict__ x_out,
    float* __restrict__ xt_out)
{
    const float TAU = 0.01f;
    const float LT  = 0.07f;          // LAMBDA_ROF * TAU
    const float INVD = 1.0f / 1.07f;  // 1/(1+LT)
    const float TH  = 0.5f;

    const int i  = blockIdx.y;
    const int j0 = (blockIdx.x * blockDim.x + threadIdx.x) * 4;
    const long base = (long)i * W + j0;

    float4 yh4 = ld4(yh + base);
    float  yhl = (j0 > 0) ? yh[base - 1] : 0.0f;  // left neighbor (0 at border)
    float4 yv4 = ld4(yv + base);
    float4 yva = (i > 0) ? ld4(yv + base - W) : make_float4(0.f, 0.f, 0.f, 0.f);

    float4 x4   = ld4(x_in + base);
    float4 img4 = ld4(img + base);

    // divergence; relies on invariants yh[:,W-1]==0, yv[H-1,:]==0
    float dv0 = (yh4.x - yhl)   + (yv4.x - yva.x);
    float dv1 = (yh4.y - yh4.x) + (yv4.y - yva.y);
    float dv2 = (yh4.z - yh4.y) + (yv4.z - yva.z);
    float dv3 = (yh4.w - yh4.z) + (yv4.w - yva.w);

    float4 xn, xtv;
    xn.x = (x4.x + TAU * dv0 + LT * img4.x) * INVD;
    xn.y = (x4.y + TAU * dv1 + LT * img4.y) * INVD;
    xn.z = (x4.z + TAU * dv2 + LT * img4.z) * INVD;
    xn.w = (x4.w + TAU * dv3 + LT * img4.w) * INVD;

    xtv.x = xn.x + TH * (xn.x - x4.x);
    xtv.y = xn.y + TH * (xn.y - x4.y);
    xtv.z = xn.z + TH * (xn.z - x4.z);
    xtv.w = xn.w + TH * (xn.w - x4.w);

    st4(x_out + base, xn);
    st4(xt_out + base, xtv);
}

extern "C" void kernel_launch(void* const* d_in, const int* in_sizes, int n_in,
                              void* d_out, int out_size, void* d_ws, size_t ws_size,
                              hipStream_t stream) {
    const float* img = (const float*)d_in[0];   // (1,H,W)
    const float* w   = (const float*)d_in[1];   // (2,H,W)
    const float* w0  = w;
    const float* w1  = w + N;

    float* xt = (float*)d_out;      // x_tilde lives in d_out the whole time
    float* x  = (float*)d_ws;       // persistent x
    float* yh = x + N;              // dual field, horizontal
    float* yv = yh + N;             // dual field, vertical

    dim3 block(256, 1, 1);
    dim3 grid(W / (4 * 256), H, 1); // (4, 4096)

    // iteration 0: x = xt = img, y = 0  (no dependence on poisoned ws/out)
    dual_update<true><<<grid, block, 0, stream>>>(img, w0, w1, yh, yv);
    primal_update<true><<<grid, block, 0, stream>>>(img, yh, yv, img, x, xt);

    for (int it = 1; it < 20; ++it) {
        dual_update<false><<<grid, block, 0, stream>>>(xt, w0, w1, yh, yv);
        primal_update<false><<<grid, block, 0, stream>>>(img, yh, yv, x, x, xt);
    }
}

// Round 2
// 2095.016 us; speedup vs baseline: 1.4446x; 1.4446x over previous
//
#include <hip/hip_runtime.h>

static constexpr int H = 4096;
static constexpr int W = 4096;
static constexpr long N = (long)H * W;

typedef _Float16 half8 __attribute__((ext_vector_type(8)));

__device__ __forceinline__ float4 ld4(const float* p) {
    return *reinterpret_cast<const float4*>(p);
}
__device__ __forceinline__ void st4(float* p, float4 v) {
    *reinterpret_cast<float4*>(p) = v;
}
__device__ __forceinline__ float clamp1(float v) {
    return fminf(fmaxf(v, -1.0f), 1.0f);
}
__device__ __forceinline__ half8 ldh8(const _Float16* p) {
    return *reinterpret_cast<const half8*>(p);
}
__device__ __forceinline__ void sth8(_Float16* p, half8 v) {
    *reinterpret_cast<half8*>(p) = v;
}

// One-time pre-pass: pack (w0,w1) into interleaved fp16 plane, 4 B/pixel.
__global__ __launch_bounds__(256) void pack_w(
    const float* __restrict__ w0,
    const float* __restrict__ w1,
    _Float16* __restrict__ wp)
{
    const int i  = blockIdx.y;
    const int j0 = (blockIdx.x * blockDim.x + threadIdx.x) * 4;
    const long base = (long)i * W + j0;
    float4 a = ld4(w0 + base);
    float4 b = ld4(w1 + base);
    half8 o;
    o[0] = (_Float16)a.x; o[1] = (_Float16)b.x;
    o[2] = (_Float16)a.y; o[3] = (_Float16)b.y;
    o[4] = (_Float16)a.z; o[5] = (_Float16)b.z;
    o[6] = (_Float16)a.w; o[7] = (_Float16)b.w;
    sth8(wp + 2 * base, o);
}

// Dual update: y = clamp(y + SIGMA * grad(xt) * w, -1, 1)
// y stored fp16 interleaved (yh,yv) per pixel. Pointwise in y -> in-place safe.
template<bool FIRST>
__global__ __launch_bounds__(256) void dual_update(
    const float* __restrict__ xt,
    const _Float16* __restrict__ wp,
    _Float16* __restrict__ y)
{
    const float SIGMA = 14.285714285714286f;  // 1/(7*0.01)
    const int i  = blockIdx.y;
    const int j0 = (blockIdx.x * blockDim.x + threadIdx.x) * 4;
    const long base = (long)i * W + j0;

    float4 c = ld4(xt + base);
    float right  = (j0 + 4 < W) ? xt[base + 4] : c.w;     // gh = 0 at last col
    float4 below = (i + 1 < H) ? ld4(xt + base + W) : c;  // gv = 0 at last row

    half8 wv = ldh8(wp + 2 * base);

    half8 yo;
    if (FIRST) {
        for (int k = 0; k < 8; ++k) yo[k] = (_Float16)0.0f;
    } else {
        yo = ldh8(y + 2 * base);
    }

    float gh0 = c.y - c.x, gh1 = c.z - c.y, gh2 = c.w - c.z, gh3 = right - c.w;
    float gv0 = below.x - c.x, gv1 = below.y - c.y;
    float gv2 = below.z - c.z, gv3 = below.w - c.w;

    half8 yn;
    yn[0] = (_Float16)clamp1((float)yo[0] + SIGMA * gh0 * (float)wv[0]);
    yn[1] = (_Float16)clamp1((float)yo[1] + SIGMA * gv0 * (float)wv[1]);
    yn[2] = (_Float16)clamp1((float)yo[2] + SIGMA * gh1 * (float)wv[2]);
    yn[3] = (_Float16)clamp1((float)yo[3] + SIGMA * gv1 * (float)wv[3]);
    yn[4] = (_Float16)clamp1((float)yo[4] + SIGMA * gh2 * (float)wv[4]);
    yn[5] = (_Float16)clamp1((float)yo[5] + SIGMA * gv2 * (float)wv[5]);
    yn[6] = (_Float16)clamp1((float)yo[6] + SIGMA * gh3 * (float)wv[6]);
    yn[7] = (_Float16)clamp1((float)yo[7] + SIGMA * gv3 * (float)wv[7]);

    sth8(y + 2 * base, yn);
}

// Primal update: x = (x + TAU*div(y) + LT*img)/(1+LT); xt = x + THETA*(x-x_old)
template<bool FIRST>
__global__ __launch_bounds__(256) void primal_update(
    const float* __restrict__ img,
    const _Float16* __restrict__ y,
    const float* __restrict__ x_in,
    float* __restrict__ x_out,
    float* __restrict__ xt_out)
{
    const float TAU = 0.01f;
    const float LT  = 0.07f;          // LAMBDA_ROF * TAU
    const float INVD = 1.0f / 1.07f;  // 1/(1+LT)
    const float TH  = 0.5f;

    const int i  = blockIdx.y;
    const int j0 = (blockIdx.x * blockDim.x + threadIdx.x) * 4;
    const long base = (long)i * W + j0;

    half8 yc = ldh8(y + 2 * base);
    float yhl = (j0 > 0) ? (float)y[2 * base - 2] : 0.0f;  // left pixel's yh
    half8 ya;
    if (i > 0) {
        ya = ldh8(y + 2 * (base - W));                     // row above (yv in odd lanes)
    } else {
        for (int k = 0; k < 8; ++k) ya[k] = (_Float16)0.0f;
    }

    float4 x4   = ld4(x_in + base);
    float4 img4 = ld4(img + base);

    // divergence; relies on invariants yh[:,W-1]==0, yv[H-1,:]==0 (exact in fp16)
    float dv0 = ((float)yc[0] - yhl)          + ((float)yc[1] - (float)ya[1]);
    float dv1 = ((float)yc[2] - (float)yc[0]) + ((float)yc[3] - (float)ya[3]);
    float dv2 = ((float)yc[4] - (float)yc[2]) + ((float)yc[5] - (float)ya[5]);
    float dv3 = ((float)yc[6] - (float)yc[4]) + ((float)yc[7] - (float)ya[7]);

    float4 xn, xtv;
    xn.x = (x4.x + TAU * dv0 + LT * img4.x) * INVD;
    xn.y = (x4.y + TAU * dv1 + LT * img4.y) * INVD;
    xn.z = (x4.z + TAU * dv2 + LT * img4.z) * INVD;
    xn.w = (x4.w + TAU * dv3 + LT * img4.w) * INVD;

    xtv.x = xn.x + TH * (xn.x - x4.x);
    xtv.y = xn.y + TH * (xn.y - x4.y);
    xtv.z = xn.z + TH * (xn.z - x4.z);
    xtv.w = xn.w + TH * (xn.w - x4.w);

    st4(x_out + base, xn);
    st4(xt_out + base, xtv);
}

extern "C" void kernel_launch(void* const* d_in, const int* in_sizes, int n_in,
                              void* d_out, int out_size, void* d_ws, size_t ws_size,
                              hipStream_t stream) {
    const float* img = (const float*)d_in[0];   // (1,H,W)
    const float* w   = (const float*)d_in[1];   // (2,H,W)
    const float* w0  = w;
    const float* w1  = w + N;

    float* xt = (float*)d_out;                       // x_tilde lives in d_out
    float*    x  = (float*)d_ws;                     // fp32 plane: 4N bytes
    _Float16* y  = (_Float16*)(x + N);               // fp16 interleaved: 4N bytes
    _Float16* wp = y + 2 * N;                        // fp16 interleaved: 4N bytes
    // total ws use: 12N = 201 MB

    dim3 block(256, 1, 1);
    dim3 grid(W / (4 * 256), H, 1); // (4, 4096)

    pack_w<<<grid, block, 0, stream>>>(w0, w1, wp);

    // iteration 0: x = xt = img, y = 0  (no dependence on poisoned ws/out)
    dual_update<true><<<grid, block, 0, stream>>>(img, wp, y);
    primal_update<true><<<grid, block, 0, stream>>>(img, y, img, x, xt);

    for (int it = 1; it < 20; ++it) {
        dual_update<false><<<grid, block, 0, stream>>>(xt, wp, y);
        primal_update<false><<<grid, block, 0, stream>>>(img, y, x, x, xt);
    }
}

// Round 3
// 1546.804 us; speedup vs baseline: 1.9567x; 1.3544x over previous
//
#include <hip/hip_runtime.h>

static constexpr int H = 4096;
static constexpr int W = 4096;
static constexpr long N = (long)H * W;

typedef _Float16 half8 __attribute__((ext_vector_type(8)));

__device__ __forceinline__ float4 ld4(const float* p) {
    return *reinterpret_cast<const float4*>(p);
}
__device__ __forceinline__ void st4(float* p, float4 v) {
    *reinterpret_cast<float4*>(p) = v;
}
__device__ __forceinline__ half8 ldh8(const _Float16* p) {
    return *reinterpret_cast<const half8*>(p);
}
__device__ __forceinline__ void sth8(_Float16* p, half8 v) {
    *reinterpret_cast<half8*>(p) = v;
}
__device__ __forceinline__ float clamp1(float v) {
    return fminf(fmaxf(v, -1.0f), 1.0f);
}

static constexpr float SIGMA = 14.285714285714286f;   // 1/(7*0.01)
static constexpr float INVD  = 1.0f / 1.07f;
static constexpr float TIV   = 0.01f / 1.07f;         // TAU * INVD
static constexpr float CF    = 0.07f / 1.07f;         // LAMBDA*TAU * INVD

// One-time pre-pass (8 px/thread):
//   wp   = interleaved fp16 (w0,w1)            [ws]
//   cimg = fp16 (LT/1.07)*img                  [lives in first half of d_out]
//   x16  = fp16 img  (x and x_tilde at iter 0) [ws]
__global__ __launch_bounds__(256) void pack_inputs(
    const float* __restrict__ img,
    const float* __restrict__ w0,
    const float* __restrict__ w1,
    _Float16* __restrict__ wp,
    _Float16* __restrict__ cimg,
    _Float16* __restrict__ x16)
{
    const int i  = blockIdx.y;
    const int j0 = (blockIdx.x * blockDim.x + threadIdx.x) * 8;
    const long base = (long)i * W + j0;

    float4 a0 = ld4(w0 + base), a1 = ld4(w0 + base + 4);
    float4 b0 = ld4(w1 + base), b1 = ld4(w1 + base + 4);
    half8 wlo, whi;
    wlo[0] = (_Float16)a0.x; wlo[1] = (_Float16)b0.x;
    wlo[2] = (_Float16)a0.y; wlo[3] = (_Float16)b0.y;
    wlo[4] = (_Float16)a0.z; wlo[5] = (_Float16)b0.z;
    wlo[6] = (_Float16)a0.w; wlo[7] = (_Float16)b0.w;
    whi[0] = (_Float16)a1.x; whi[1] = (_Float16)b1.x;
    whi[2] = (_Float16)a1.y; whi[3] = (_Float16)b1.y;
    whi[4] = (_Float16)a1.z; whi[5] = (_Float16)b1.z;
    whi[6] = (_Float16)a1.w; whi[7] = (_Float16)b1.w;
    sth8(wp + 2 * base, wlo);
    sth8(wp + 2 * base + 8, whi);

    float4 m0 = ld4(img + base), m1 = ld4(img + base + 4);
    half8 cv, xv;
    cv[0] = (_Float16)(CF * m0.x); xv[0] = (_Float16)m0.x;
    cv[1] = (_Float16)(CF * m0.y); xv[1] = (_Float16)m0.y;
    cv[2] = (_Float16)(CF * m0.z); xv[2] = (_Float16)m0.z;
    cv[3] = (_Float16)(CF * m0.w); xv[3] = (_Float16)m0.w;
    cv[4] = (_Float16)(CF * m1.x); xv[4] = (_Float16)m1.x;
    cv[5] = (_Float16)(CF * m1.y); xv[5] = (_Float16)m1.y;
    cv[6] = (_Float16)(CF * m1.z); xv[6] = (_Float16)m1.z;
    cv[7] = (_Float16)(CF * m1.w); xv[7] = (_Float16)m1.w;
    sth8(cimg + base, cv);
    sth8(x16 + base, xv);
}

// Dual: y = clamp(y + SIGMA * grad(xt) * w, -1, 1), fp16 state, 8 px/thread.
// In-place on y (pointwise). FIRST: y_old = 0 (skip poisoned read).
template<bool FIRST>
__global__ __launch_bounds__(256) void dual_update(
    const _Float16* __restrict__ xt,
    const _Float16* __restrict__ wp,
    _Float16* __restrict__ y)
{
    const int i  = blockIdx.y;
    const int j0 = (blockIdx.x * blockDim.x + threadIdx.x) * 8;
    const long base = (long)i * W + j0;

    half8 c = ldh8(xt + base);
    _Float16 right = (j0 + 8 < W) ? xt[base + 8] : c[7];   // gh = 0 at last col
    half8 below = (i + 1 < H) ? ldh8(xt + base + W) : c;   // gv = 0 at last row

    half8 w0v = ldh8(wp + 2 * base);
    half8 w1v = ldh8(wp + 2 * base + 8);

    half8 y0, y1;
    if (!FIRST) {
        y0 = ldh8(y + 2 * base);
        y1 = ldh8(y + 2 * base + 8);
    }

    float cc[8], bb[8];
#pragma unroll
    for (int k = 0; k < 8; ++k) { cc[k] = (float)c[k]; bb[k] = (float)below[k]; }
    float rightf = (float)right;

    half8 yn0, yn1;
#pragma unroll
    for (int k = 0; k < 8; ++k) {
        float gh = ((k < 7) ? cc[k + 1] : rightf) - cc[k];
        float gv = bb[k] - cc[k];
        float wh  = (float)((k < 4) ? w0v[2 * k]     : w1v[2 * (k - 4)]);
        float wv  = (float)((k < 4) ? w0v[2 * k + 1] : w1v[2 * (k - 4) + 1]);
        float yh = FIRST ? 0.0f : (float)((k < 4) ? y0[2 * k]     : y1[2 * (k - 4)]);
        float yv = FIRST ? 0.0f : (float)((k < 4) ? y0[2 * k + 1] : y1[2 * (k - 4) + 1]);
        yh = clamp1(yh + SIGMA * gh * wh);
        yv = clamp1(yv + SIGMA * gv * wv);
        if (k < 4) { yn0[2 * k] = (_Float16)yh; yn0[2 * k + 1] = (_Float16)yv; }
        else       { yn1[2 * (k - 4)] = (_Float16)yh; yn1[2 * (k - 4) + 1] = (_Float16)yv; }
    }
    sth8(y + 2 * base, yn0);
    sth8(y + 2 * base + 8, yn1);
}

// Primal: x = x*INVD + TIV*div(y) + cimg; xt = 1.5x - 0.5x_old. fp16 state.
// LAST: read img fp32 (cimg lives in d_out and is being replaced), write fp32 out.
template<bool LAST>
__global__ __launch_bounds__(256) void primal_update(
    const _Float16* __restrict__ cimg,
    const float* __restrict__ img,
    const _Float16* __restrict__ y,
    const _Float16* __restrict__ x_in,
    _Float16* __restrict__ x_out,
    _Float16* __restrict__ xt_out,
    float* __restrict__ out)
{
    const int i  = blockIdx.y;
    const int j0 = (blockIdx.x * blockDim.x + threadIdx.x) * 8;
    const long base = (long)i * W + j0;

    half8 yc0 = ldh8(y + 2 * base);
    half8 yc1 = ldh8(y + 2 * base + 8);
    half8 ya0, ya1;
    if (i > 0) {
        ya0 = ldh8(y + 2 * (base - W));
        ya1 = ldh8(y + 2 * (base - W) + 8);
    } else {
#pragma unroll
        for (int k = 0; k < 8; ++k) { ya0[k] = (_Float16)0.0f; ya1[k] = (_Float16)0.0f; }
    }
    float yhl = (j0 > 0) ? (float)y[2 * base - 2] : 0.0f;

    half8 xv = ldh8(x_in + base);

    float f[8];
    if (LAST) {
        float4 m0 = ld4(img + base), m1 = ld4(img + base + 4);
        f[0] = CF * m0.x; f[1] = CF * m0.y; f[2] = CF * m0.z; f[3] = CF * m0.w;
        f[4] = CF * m1.x; f[5] = CF * m1.y; f[6] = CF * m1.z; f[7] = CF * m1.w;
    } else {
        half8 cv = ldh8(cimg + base);
#pragma unroll
        for (int k = 0; k < 8; ++k) f[k] = (float)cv[k];
    }

    float prev_yh = yhl;
    float xt_res[8];
    half8 xn16, xt16v;
#pragma unroll
    for (int k = 0; k < 8; ++k) {
        float yh  = (float)((k < 4) ? yc0[2 * k]     : yc1[2 * (k - 4)]);
        float yv  = (float)((k < 4) ? yc0[2 * k + 1] : yc1[2 * (k - 4) + 1]);
        float yva = (float)((k < 4) ? ya0[2 * k + 1] : ya1[2 * (k - 4) + 1]);
        float dv = (yh - prev_yh) + (yv - yva);
        prev_yh = yh;
        float xo = (float)xv[k];
        float xn = xo * INVD + TIV * dv + f[k];
        float xt = 1.5f * xn - 0.5f * xo;
        if (LAST) {
            xt_res[k] = xt;
        } else {
            xn16[k]  = (_Float16)xn;
            xt16v[k] = (_Float16)xt;
        }
    }

    if (LAST) {
        float4 o0 = make_float4(xt_res[0], xt_res[1], xt_res[2], xt_res[3]);
        float4 o1 = make_float4(xt_res[4], xt_res[5], xt_res[6], xt_res[7]);
        st4(out + base, o0);
        st4(out + base + 4, o1);
    } else {
        sth8(x_out + base, xn16);
        sth8(xt_out + base, xt16v);
    }
}

extern "C" void kernel_launch(void* const* d_in, const int* in_sizes, int n_in,
                              void* d_out, int out_size, void* d_ws, size_t ws_size,
                              hipStream_t stream) {
    const float* img = (const float*)d_in[0];   // (1,H,W)
    const float* w0  = (const float*)d_in[1];   // (2,H,W)
    const float* w1  = w0 + N;

    float* out = (float*)d_out;
    // cimg scratch lives in the first 2N bytes of d_out; the LAST primal
    // overwrites all of d_out with the fp32 result (and reads img instead).
    _Float16* cimg = (_Float16*)d_out;

    _Float16* wp   = (_Float16*)d_ws;   // 2N elems (4N bytes) interleaved (w0,w1)
    _Float16* y    = wp + 2 * N;        // 2N elems (4N bytes) interleaved (yh,yv)
    _Float16* x16  = y + 2 * N;         // N elems (2N bytes)
    _Float16* xt16 = x16 + N;           // N elems (2N bytes)  -> total 12N bytes

    dim3 block(256, 1, 1);
    dim3 grid(W / (8 * 256), H, 1);     // (2, 4096)

    pack_inputs<<<grid, block, 0, stream>>>(img, w0, w1, wp, cimg, x16);

    // iter 0: xt = x = fp16(img), y = 0
    dual_update<true><<<grid, block, 0, stream>>>(x16, wp, y);
    primal_update<false><<<grid, block, 0, stream>>>(cimg, nullptr, y, x16, x16, xt16, nullptr);

    for (int it = 1; it < 19; ++it) {
        dual_update<false><<<grid, block, 0, stream>>>(xt16, wp, y);
        primal_update<false><<<grid, block, 0, stream>>>(cimg, nullptr, y, x16, x16, xt16, nullptr);
    }

    // iter 19: write fp32 x_tilde into d_out (replacing cimg scratch)
    dual_update<false><<<grid, block, 0, stream>>>(xt16, wp, y);
    primal_update<true><<<grid, block, 0, stream>>>(nullptr, img, y, x16, nullptr, nullptr, out);
}

// Round 4
// 1034.361 us; speedup vs baseline: 2.9260x; 1.4954x over previous
//
#include <hip/hip_runtime.h>

static constexpr int H = 4096;
static constexpr int W = 4096;
static constexpr long N = (long)H * W;

static constexpr int TILE = 64;
static constexpr int HALO = 20;              // one per iteration per side
static constexpr int R    = TILE + 2*HALO;   // 104 region
static constexpr int S    = R;               // stride in halfs = 208 B (16B-aligned)
static constexpr int PS   = R * S;           // plane size in halfs (10816)
static constexpr int NCH  = R * (R/8);       // 1352 half8-chunk tasks per phase
static constexpr int NT   = 512;             // threads per block

static constexpr float SIGMA = 14.285714285714286f;  // 1/(7*0.01)
static constexpr float INVD  = 1.0f / 1.07f;
static constexpr float TIV   = 0.01f / 1.07f;        // TAU/(1+LT)
static constexpr float CF    = 0.07f / 1.07f;        // LAMBDA*TAU/(1+LT)

typedef _Float16 half8  __attribute__((ext_vector_type(8)));
typedef _Float16 half4v __attribute__((ext_vector_type(4)));

__device__ __forceinline__ half8 splat8(float f) {
    _Float16 h = (_Float16)f;
    half8 v = {h, h, h, h, h, h, h, h};
    return v;
}
__device__ __forceinline__ half8 clamp8(half8 v) {
    v = __builtin_elementwise_min(v, splat8(1.0f));
    v = __builtin_elementwise_max(v, splat8(-1.0f));
    return v;
}

extern __shared__ _Float16 lds[];

// All 20 primal-dual iterations for one 64x64 output tile, state in LDS.
// BCs are data-encoded: out-of-image / last-col / last-row pixels get w=0,
// so their y stays 0 forever, which reproduces the pad/divergence BCs.
// Halo pixels become progressively invalid (1/side/iter); halo=20 covers it.
__global__ __launch_bounds__(NT) void fused_pd(
    const float* __restrict__ img,
    const float* __restrict__ wg,    // (2,H,W): wg[0]=w_h, wg[N]=w_v
    float* __restrict__ out)
{
    _Float16* __restrict__ xtp = lds;            // x_tilde
    _Float16* __restrict__ xp  = lds + 1*PS;     // x
    _Float16* __restrict__ yhp = lds + 2*PS;     // y horizontal
    _Float16* __restrict__ yvp = lds + 3*PS;     // y vertical
    _Float16* __restrict__ whp = lds + 4*PS;     // SIGMA*w_h (0 at BC)
    _Float16* __restrict__ wvp = lds + 5*PS;     // SIGMA*w_v (0 at BC)
    _Float16* __restrict__ cip = lds + 6*PS;     // CF*img

    const int tid = threadIdx.x;
    const int gi0 = blockIdx.y * TILE - HALO;
    const int gj0 = blockIdx.x * TILE - HALO;
    const bool interior = (gi0 >= 0) && (gj0 >= 0) && (gi0 + R <= H) && (gj0 + R <= W);

    // ---------------- load & init ----------------
    for (int t = tid; t < NCH; t += NT) {
        const int i  = t / 13;
        const int j0 = (t - i * 13) * 8;
        const int gi = gi0 + i;
        const int gj = gj0 + j0;
        float im[8], wh[8], wv[8];
        if (interior) {
            // 16B-aligned: gj = 64a - 20 + 8c  ->  gj % 4 == 0
            const float4* ip = reinterpret_cast<const float4*>(img + (long)gi * W + gj);
            float4 a = ip[0], b = ip[1];
            im[0]=a.x; im[1]=a.y; im[2]=a.z; im[3]=a.w;
            im[4]=b.x; im[5]=b.y; im[6]=b.z; im[7]=b.w;
            const float4* hp = reinterpret_cast<const float4*>(wg + (long)gi * W + gj);
            float4 c = hp[0], d = hp[1];
            wh[0]=c.x*SIGMA; wh[1]=c.y*SIGMA; wh[2]=c.z*SIGMA; wh[3]=c.w*SIGMA;
            wh[4]=d.x*SIGMA; wh[5]=d.y*SIGMA; wh[6]=d.z*SIGMA; wh[7]=d.w*SIGMA;
            const float4* vp = reinterpret_cast<const float4*>(wg + N + (long)gi * W + gj);
            float4 e = vp[0], f = vp[1];
            wv[0]=e.x*SIGMA; wv[1]=e.y*SIGMA; wv[2]=e.z*SIGMA; wv[3]=e.w*SIGMA;
            wv[4]=f.x*SIGMA; wv[5]=f.y*SIGMA; wv[6]=f.z*SIGMA; wv[7]=f.w*SIGMA;
            // interior regions never touch row H-1 / col W-1, no BC zeroing needed
        } else {
            const int gic = min(max(gi, 0), H - 1);
            const bool rowin = (gi >= 0) && (gi < H);
#pragma unroll
            for (int k = 0; k < 8; ++k) {
                const int gjk = gj + k;
                const int gjc = min(max(gjk, 0), W - 1);
                const bool inim = rowin && (gjk >= 0) && (gjk < W);
                const long o = (long)gic * W + gjc;
                im[k] = img[o];
                wh[k] = (inim && gjk < W - 1) ? SIGMA * wg[o]     : 0.0f;
                wv[k] = (inim && gi  < H - 1) ? SIGMA * wg[N + o] : 0.0f;
            }
        }
        half8 imv, whv, wvv, civ;
#pragma unroll
        for (int k = 0; k < 8; ++k) {
            imv[k] = (_Float16)im[k];
            whv[k] = (_Float16)wh[k];
            wvv[k] = (_Float16)wv[k];
            civ[k] = (_Float16)(CF * im[k]);
        }
        const int base = i * S + j0;
        *reinterpret_cast<half8*>(xtp + base) = imv;   // xt = img
        *reinterpret_cast<half8*>(xp  + base) = imv;   // x  = img
        *reinterpret_cast<half8*>(whp + base) = whv;
        *reinterpret_cast<half8*>(wvp + base) = wvv;
        *reinterpret_cast<half8*>(cip + base) = civ;
        const half8 z = splat8(0.0f);
        *reinterpret_cast<half8*>(yhp + base) = z;     // y = 0
        *reinterpret_cast<half8*>(yvp + base) = z;
    }
    __syncthreads();

    // precompute this thread's chunk bases (2 or 3 tasks per thread)
    const int t0 = tid, t1 = tid + NT, t2 = tid + 2 * NT;
    const int i0_ = t0 / 13, i1_ = t1 / 13, i2_ = t2 / 13;
    const int b0 = i0_ * S + (t0 - i0_ * 13) * 8;
    const int b1 = i1_ * S + (t1 - i1_ * 13) * 8;
    const int b2 = i2_ * S + (t2 - i2_ * 13) * 8;
    const bool has2 = (t2 < NCH);

    for (int it = 0; it < 20; ++it) {
        // -------- dual: y = clamp(y + grad(xt) * (SIGMA*w)) --------
        auto dualT = [&](int base) {
            half8 cv = *reinterpret_cast<const half8*>(xtp + base);
            _Float16 rt = xtp[base + 8];                       // right neighbor
            half8 bv = *reinterpret_cast<const half8*>(xtp + base + S);  // row below
            half8 sh = __builtin_shufflevector(cv, cv, 1, 2, 3, 4, 5, 6, 7, 7);
            sh[7] = rt;
            half8 gh = sh - cv;
            half8 gv = bv - cv;
            half8 yh = *reinterpret_cast<const half8*>(yhp + base);
            half8 yv = *reinterpret_cast<const half8*>(yvp + base);
            yh = clamp8(yh + gh * *reinterpret_cast<const half8*>(whp + base));
            yv = clamp8(yv + gv * *reinterpret_cast<const half8*>(wvp + base));
            *reinterpret_cast<half8*>(yhp + base) = yh;
            *reinterpret_cast<half8*>(yvp + base) = yv;
        };
        dualT(b0); dualT(b1); if (has2) dualT(b2);
        __syncthreads();

        // -------- primal: x = x*INVD + TIV*div(y) + CF*img; xt = 1.5x - 0.5x_old --------
        auto primT = [&](int base) {
            half8 yh = *reinterpret_cast<const half8*>(yhp + base);
            _Float16 yl = yhp[base - 1];                       // left neighbor
            half8 ysh = __builtin_shufflevector(yh, yh, 0, 0, 1, 2, 3, 4, 5, 6);
            ysh[0] = yl;
            half8 yv  = *reinterpret_cast<const half8*>(yvp + base);
            half8 yva = *reinterpret_cast<const half8*>(yvp + base - S); // row above
            half8 dv16 = (yh - ysh) + (yv - yva);
            half8 xv = *reinterpret_cast<const half8*>(xp + base);
            half8 ci = *reinterpret_cast<const half8*>(cip + base);
            half8 xn16, xt16;
#pragma unroll
            for (int k = 0; k < 8; ++k) {
                float x32 = (float)xv[k];
                float n = fmaf(x32, INVD, fmaf(TIV, (float)dv16[k], (float)ci[k]));
                xn16[k] = (_Float16)n;
                xt16[k] = (_Float16)(1.5f * n - 0.5f * x32);
            }
            *reinterpret_cast<half8*>(xp  + base) = xn16;
            *reinterpret_cast<half8*>(xtp + base) = xt16;
        };
        primT(b0); primT(b1); if (has2) primT(b2);
        __syncthreads();
    }

    // ---------------- store center 64x64 as fp32 ----------------
    {
        const int r = tid >> 3;          // 0..63
        const int c = tid & 7;           // 0..7  (8 px each)
        const int base = (HALO + r) * S + HALO + c * 8;   // 8B-aligned
        half4v a = *reinterpret_cast<const half4v*>(xtp + base);
        half4v b = *reinterpret_cast<const half4v*>(xtp + base + 4);
        float4 o0 = make_float4((float)a[0], (float)a[1], (float)a[2], (float)a[3]);
        float4 o1 = make_float4((float)b[0], (float)b[1], (float)b[2], (float)b[3]);
        const long g = (long)(blockIdx.y * TILE + r) * W + blockIdx.x * TILE + c * 8;
        *reinterpret_cast<float4*>(out + g)     = o0;
        *reinterpret_cast<float4*>(out + g + 4) = o1;
    }
}

extern "C" void kernel_launch(void* const* d_in, const int* in_sizes, int n_in,
                              void* d_out, int out_size, void* d_ws, size_t ws_size,
                              hipStream_t stream) {
    const float* img = (const float*)d_in[0];   // (1,H,W)
    const float* wg  = (const float*)d_in[1];   // (2,H,W)
    float* out = (float*)d_out;

    constexpr int LDS_BYTES = 7 * PS * 2;       // 151424 B (< 160 KiB/CU)
    // >64 KiB dynamic LDS requires the attribute; host-side call, capture-safe.
    (void)hipFuncSetAttribute((const void*)fused_pd,
                              hipFuncAttributeMaxDynamicSharedMemorySize, LDS_BYTES);

    dim3 grid(W / TILE, H / TILE);              // 64 x 64 = 4096 blocks
    fused_pd<<<grid, dim3(NT), LDS_BYTES, stream>>>(img, wg, out);
}

// Round 5
// 806.319 us; speedup vs baseline: 3.7536x; 1.2828x over previous
//
#include <hip/hip_runtime.h>

static constexpr int H = 4096;
static constexpr int W = 4096;
static constexpr long N = (long)H * W;

static constexpr int TILE = 64;
static constexpr int HALO = 20;              // one per iteration per side
static constexpr int R    = TILE + 2*HALO;   // 104 region
static constexpr int S    = R;               // row stride (halfs)
static constexpr int PS   = R * S;           // plane size (halfs)
static constexpr int NCH  = R * (R/8);       // 1352 half8-chunk tasks
static constexpr int NT   = 512;

static constexpr float SIGMA = 14.285714285714286f;  // 1/(7*0.01)
static constexpr float INVD  = 1.0f / 1.07f;
static constexpr float TIV   = 0.01f / 1.07f;        // TAU/(1+LT)
static constexpr float CF    = 0.07f / 1.07f;        // LAMBDA*TAU/(1+LT)

typedef _Float16 half8  __attribute__((ext_vector_type(8)));
typedef _Float16 half4v __attribute__((ext_vector_type(4)));
typedef float    float8 __attribute__((ext_vector_type(8)));

__device__ __forceinline__ half8 splat8(float f) {
    _Float16 h = (_Float16)f;
    half8 v = {h, h, h, h, h, h, h, h};
    return v;
}
__device__ __forceinline__ half8 clamp8(half8 v) {
    v = __builtin_elementwise_min(v, splat8(1.0f));
    v = __builtin_elementwise_max(v, splat8(-1.0f));
    return v;
}

// All 20 iterations fused; LDS holds only the cross-thread planes (xt, yh, yv).
// Thread-private state (sigma*w, CF*img, x fp32, own y) lives in registers.
// BCs are data-encoded (w=0 outside image / last col / last row). Halo pixels
// invalidate 1/side/iter; HALO=20 covers 20 iterations. The out-of-plane halo
// reads at region row 0 land in the preceding plane: always-written, finite,
// and feed only halo pixels that are invalid by then anyway.
__global__ __launch_bounds__(NT, 4) void fused_pd(
    const float* __restrict__ img,
    const float* __restrict__ wg,    // (2,H,W): wg[0]=w_h, wg[N]=w_v
    float* __restrict__ out)
{
    __shared__ _Float16 lds_s[3 * PS];          // 64,896 B -> 2 blocks/CU
    _Float16* __restrict__ xtp = lds_s;         // x_tilde
    _Float16* __restrict__ yhp = lds_s + PS;    // y horizontal
    _Float16* __restrict__ yvp = lds_s + 2*PS;  // y vertical

    const int tid = threadIdx.x;
    const int gi0 = blockIdx.y * TILE - HALO;
    const int gj0 = blockIdx.x * TILE - HALO;
    const bool interior = (gi0 >= 0) && (gj0 >= 0) && (gi0 + R <= H) && (gj0 + R <= W);

    const int t0 = tid, t1 = tid + NT, t2 = tid + 2 * NT;
    const int i0_ = t0 / 13, i1_ = t1 / 13, i2_ = t2 / 13;
    const int b0 = i0_ * S + (t0 - i0_ * 13) * 8;
    const int b1 = i1_ * S + (t1 - i1_ * 13) * 8;
    const int b2 = i2_ * S + (t2 - i2_ * 13) * 8;
    const bool act2 = (t2 < NCH);

    // persistent per-chunk register state
    half8 wh0, wh1, wh2, wv0, wv1, wv2;   // SIGMA*w
    half8 ci0, ci1, ci2;                  // CF*img
    float8 x0, x1, x2;                    // fp32 x
    half8 yh0, yh1, yh2, yv0, yv1, yv2;   // dual state

    // ---------------- load & init ----------------
    auto loadC = [&](int t, half8& whr, half8& wvr, half8& cir, float8& xr) {
        const int i  = t / 13;
        const int j0 = (t - i * 13) * 8;
        const int gi = gi0 + i;
        const int gj = gj0 + j0;
        float im[8], wh[8], wv[8];
        if (interior) {
            const float4* ip = reinterpret_cast<const float4*>(img + (long)gi * W + gj);
            float4 a = ip[0], b = ip[1];
            im[0]=a.x; im[1]=a.y; im[2]=a.z; im[3]=a.w;
            im[4]=b.x; im[5]=b.y; im[6]=b.z; im[7]=b.w;
            const float4* hp = reinterpret_cast<const float4*>(wg + (long)gi * W + gj);
            float4 c = hp[0], d = hp[1];
            wh[0]=c.x*SIGMA; wh[1]=c.y*SIGMA; wh[2]=c.z*SIGMA; wh[3]=c.w*SIGMA;
            wh[4]=d.x*SIGMA; wh[5]=d.y*SIGMA; wh[6]=d.z*SIGMA; wh[7]=d.w*SIGMA;
            const float4* vp = reinterpret_cast<const float4*>(wg + N + (long)gi * W + gj);
            float4 e = vp[0], f = vp[1];
            wv[0]=e.x*SIGMA; wv[1]=e.y*SIGMA; wv[2]=e.z*SIGMA; wv[3]=e.w*SIGMA;
            wv[4]=f.x*SIGMA; wv[5]=f.y*SIGMA; wv[6]=f.z*SIGMA; wv[7]=f.w*SIGMA;
        } else {
            const int gic = min(max(gi, 0), H - 1);
            const bool rowin = (gi >= 0) && (gi < H);
#pragma unroll
            for (int k = 0; k < 8; ++k) {
                const int gjk = gj + k;
                const int gjc = min(max(gjk, 0), W - 1);
                const bool inim = rowin && (gjk >= 0) && (gjk < W);
                const long o = (long)gic * W + gjc;
                im[k] = img[o];
                wh[k] = (inim && gjk < W - 1) ? SIGMA * wg[o]     : 0.0f;
                wv[k] = (inim && gi  < H - 1) ? SIGMA * wg[N + o] : 0.0f;
            }
        }
        half8 imv;
#pragma unroll
        for (int k = 0; k < 8; ++k) {
            imv[k] = (_Float16)im[k];
            whr[k] = (_Float16)wh[k];
            wvr[k] = (_Float16)wv[k];
            cir[k] = (_Float16)(CF * im[k]);
            xr[k]  = im[k];
        }
        *reinterpret_cast<half8*>(xtp + i * S + j0) = imv;   // xt = img
    };
    loadC(t0, wh0, wv0, ci0, x0);
    loadC(t1, wh1, wv1, ci1, x1);
    if (act2) loadC(t2, wh2, wv2, ci2, x2);
    yh0 = splat8(0.f); yh1 = splat8(0.f); yh2 = splat8(0.f);
    yv0 = splat8(0.f); yv1 = splat8(0.f); yv2 = splat8(0.f);
    __syncthreads();

    for (int it = 0; it < 20; ++it) {
        // -------- dual: y = clamp(y + grad(xt) * (SIGMA*w)); y stays in regs,
        //          LDS copy written only for neighbors' halo reads --------
        {
            half8 cv0_ = *reinterpret_cast<const half8*>(xtp + b0);
            half8 bv0_ = *reinterpret_cast<const half8*>(xtp + b0 + S);
            _Float16 rt0 = xtp[b0 + 8];
            half8 cv1_ = *reinterpret_cast<const half8*>(xtp + b1);
            half8 bv1_ = *reinterpret_cast<const half8*>(xtp + b1 + S);
            _Float16 rt1 = xtp[b1 + 8];
            half8 cv2_, bv2_; _Float16 rt2 = (_Float16)0.f;
            if (act2) {
                cv2_ = *reinterpret_cast<const half8*>(xtp + b2);
                bv2_ = *reinterpret_cast<const half8*>(xtp + b2 + S);
                rt2 = xtp[b2 + 8];
            }
            auto dualC = [&](int base, half8 cv, half8 bv, _Float16 rt,
                             half8 wh, half8 wv, half8& yh, half8& yv) {
                half8 sh = __builtin_shufflevector(cv, cv, 1, 2, 3, 4, 5, 6, 7, 7);
                sh[7] = rt;
                yh = clamp8(yh + (sh - cv) * wh);
                yv = clamp8(yv + (bv - cv) * wv);
                *reinterpret_cast<half8*>(yhp + base) = yh;
                *reinterpret_cast<half8*>(yvp + base) = yv;
            };
            dualC(b0, cv0_, bv0_, rt0, wh0, wv0, yh0, yv0);
            dualC(b1, cv1_, bv1_, rt1, wh1, wv1, yh1, yv1);
            if (act2) dualC(b2, cv2_, bv2_, rt2, wh2, wv2, yh2, yv2);
        }
        __syncthreads();

        // -------- primal: x = x*INVD + TIV*div(y) + CF*img (fp32 regs);
        //          xt = 1.5x - 0.5x_old -> LDS fp16 --------
        {
            _Float16 yl0 = yhp[b0 - 1];
            half8   yva0 = *reinterpret_cast<const half8*>(yvp + b0 - S);
            _Float16 yl1 = yhp[b1 - 1];
            half8   yva1 = *reinterpret_cast<const half8*>(yvp + b1 - S);
            _Float16 yl2 = (_Float16)0.f; half8 yva2;
            if (act2) {
                yl2  = yhp[b2 - 1];
                yva2 = *reinterpret_cast<const half8*>(yvp + b2 - S);
            }
            auto primC = [&](int base, _Float16 yl, half8 yva,
                             half8 yh, half8 yv, half8 ci, float8& x) {
                half8 ysh = __builtin_shufflevector(yh, yh, 0, 0, 1, 2, 3, 4, 5, 6);
                ysh[0] = yl;
                half8 dv16 = (yh - ysh) + (yv - yva);
                float8 dv = __builtin_convertvector(dv16, float8);
                float8 ci32 = __builtin_convertvector(ci, float8);
                float8 xn = x * INVD + dv * TIV + ci32;
                float8 xtf = xn * 1.5f - x * 0.5f;
                x = xn;
                *reinterpret_cast<half8*>(xtp + base) =
                    __builtin_convertvector(xtf, half8);
            };
            primC(b0, yl0, yva0, yh0, yv0, ci0, x0);
            primC(b1, yl1, yva1, yh1, yv1, ci1, x1);
            if (act2) primC(b2, yl2, yva2, yh2, yv2, ci2, x2);
        }
        __syncthreads();
    }

    // ---------------- store center 64x64 as fp32 ----------------
    {
        const int r = tid >> 3;          // 0..63
        const int c = tid & 7;           // 0..7
        const int base = (HALO + r) * S + HALO + c * 8;   // 8B-aligned
        half4v a = *reinterpret_cast<const half4v*>(xtp + base);
        half4v b = *reinterpret_cast<const half4v*>(xtp + base + 4);
        float4 o0 = make_float4((float)a[0], (float)a[1], (float)a[2], (float)a[3]);
        float4 o1 = make_float4((float)b[0], (float)b[1], (float)b[2], (float)b[3]);
        const long g = (long)(blockIdx.y * TILE + r) * W + blockIdx.x * TILE + c * 8;
        *reinterpret_cast<float4*>(out + g)     = o0;
        *reinterpret_cast<float4*>(out + g + 4) = o1;
    }
}

extern "C" void kernel_launch(void* const* d_in, const int* in_sizes, int n_in,
                              void* d_out, int out_size, void* d_ws, size_t ws_size,
                              hipStream_t stream) {
    const float* img = (const float*)d_in[0];   // (1,H,W)
    const float* wg  = (const float*)d_in[1];   // (2,H,W)
    float* out = (float*)d_out;

    dim3 grid(W / TILE, H / TILE);              // 64 x 64 = 4096 blocks
    fused_pd<<<grid, dim3(NT), 0, stream>>>(img, wg, out);
}

// Round 6
// 719.898 us; speedup vs baseline: 4.2042x; 1.1200x over previous
//
#include <hip/hip_runtime.h>

static constexpr int H = 4096;
static constexpr int W = 4096;
static constexpr long N = (long)H * W;

static constexpr int TILE = 64;
static constexpr int HALO = 20;              // one per iteration per side
static constexpr int R    = TILE + 2*HALO;   // 104 region
static constexpr int S    = R;               // row stride (halfs)
static constexpr int PS   = R * S;           // plane size (halfs)
static constexpr int NCH  = R * (R/8);       // 1352 half8-chunk tasks
static constexpr int NT   = 512;

static constexpr float SIGMA = 14.285714285714286f;  // 1/(7*0.01)
static constexpr float INVD  = 1.0f / 1.07f;
static constexpr float TIV   = 0.01f / 1.07f;        // TAU/(1+LT)
static constexpr float CF    = 0.07f / 1.07f;        // LAMBDA*TAU/(1+LT)

typedef _Float16 half8  __attribute__((ext_vector_type(8)));
typedef _Float16 half4v __attribute__((ext_vector_type(4)));
typedef float    float8 __attribute__((ext_vector_type(8)));

__device__ __forceinline__ half8 splat8(float f) {
    _Float16 h = (_Float16)f;
    half8 v = {h, h, h, h, h, h, h, h};
    return v;
}
__device__ __forceinline__ half8 clamp8(half8 v) {
    v = __builtin_elementwise_min(v, splat8(1.0f));
    v = __builtin_elementwise_max(v, splat8(-1.0f));
    return v;
}

// All 20 iterations fused. LDS holds xt plane, yv plane, and a compact yh
// edge array (only element 7 of each chunk is ever read cross-thread).
// Thread-private state (sigma*w, CF*img, x fp32, own yh/yv) in registers.
// BCs data-encoded (w=0 outside image / last col / last row); halo pixels
// invalidate 1/side/iter, HALO=20 covers 20 iterations. All out-of-range
// halo reads land on finite, always-written LDS and feed only cone-invalid
// pixels (same argument as previous rounds).
__global__ __launch_bounds__(NT, 2) void fused_pd(
    const float* __restrict__ img,
    const float* __restrict__ wg,    // (2,H,W): wg[0]=w_h, wg[N]=w_v
    float* __restrict__ out)
{
    __shared__ _Float16 lds_s[2 * PS + NCH + 2];   // 45,972 B
    _Float16* __restrict__ xtp = lds_s;            // x_tilde plane
    _Float16* __restrict__ yvp = lds_s + PS;       // y vertical plane
    _Float16* __restrict__ yhe = lds_s + 2 * PS;   // yh edges: yhe[t+1] = yh[7] of chunk t

    const int tid = threadIdx.x;
    const int gi0 = blockIdx.y * TILE - HALO;
    const int gj0 = blockIdx.x * TILE - HALO;
    const bool interior = (gi0 >= 0) && (gj0 >= 0) && (gi0 + R <= H) && (gj0 + R <= W);

    const int t0 = tid, t1 = tid + NT, t2 = tid + 2 * NT;
    const int i0_ = t0 / 13, i1_ = t1 / 13, i2_ = t2 / 13;
    const int b0 = i0_ * S + (t0 - i0_ * 13) * 8;
    const int b1 = i1_ * S + (t1 - i1_ * 13) * 8;
    const int b2 = i2_ * S + (t2 - i2_ * 13) * 8;
    const bool act2 = (t2 < NCH);

    // persistent per-chunk register state
    half8 wh0, wh1, wh2, wv0, wv1, wv2;   // SIGMA*w
    half8 ci0, ci1, ci2;                  // CF*img (fp16)
    float8 x0, x1, x2;                    // x (fp32 accumulation)
    half8 yh0, yh1, yh2, yv0, yv1, yv2;   // dual state

    // ---------------- load & init ----------------
    auto loadC = [&](int t, half8& whr, half8& wvr, half8& cir, float8& xr) {
        const int i  = t / 13;
        const int j0 = (t - i * 13) * 8;
        const int gi = gi0 + i;
        const int gj = gj0 + j0;
        float im[8], wh[8], wv[8];
        if (interior) {
            const float4* ip = reinterpret_cast<const float4*>(img + (long)gi * W + gj);
            float4 a = ip[0], b = ip[1];
            im[0]=a.x; im[1]=a.y; im[2]=a.z; im[3]=a.w;
            im[4]=b.x; im[5]=b.y; im[6]=b.z; im[7]=b.w;
            const float4* hp = reinterpret_cast<const float4*>(wg + (long)gi * W + gj);
            float4 c = hp[0], d = hp[1];
            wh[0]=c.x*SIGMA; wh[1]=c.y*SIGMA; wh[2]=c.z*SIGMA; wh[3]=c.w*SIGMA;
            wh[4]=d.x*SIGMA; wh[5]=d.y*SIGMA; wh[6]=d.z*SIGMA; wh[7]=d.w*SIGMA;
            const float4* vp = reinterpret_cast<const float4*>(wg + N + (long)gi * W + gj);
            float4 e = vp[0], f = vp[1];
            wv[0]=e.x*SIGMA; wv[1]=e.y*SIGMA; wv[2]=e.z*SIGMA; wv[3]=e.w*SIGMA;
            wv[4]=f.x*SIGMA; wv[5]=f.y*SIGMA; wv[6]=f.z*SIGMA; wv[7]=f.w*SIGMA;
        } else {
            const int gic = min(max(gi, 0), H - 1);
            const bool rowin = (gi >= 0) && (gi < H);
#pragma unroll
            for (int k = 0; k < 8; ++k) {
                const int gjk = gj + k;
                const int gjc = min(max(gjk, 0), W - 1);
                const bool inim = rowin && (gjk >= 0) && (gjk < W);
                const long o = (long)gic * W + gjc;
                im[k] = img[o];
                wh[k] = (inim && gjk < W - 1) ? SIGMA * wg[o]     : 0.0f;
                wv[k] = (inim && gi  < H - 1) ? SIGMA * wg[N + o] : 0.0f;
            }
        }
        half8 imv;
#pragma unroll
        for (int k = 0; k < 8; ++k) {
            imv[k] = (_Float16)im[k];
            whr[k] = (_Float16)wh[k];
            wvr[k] = (_Float16)wv[k];
            cir[k] = (_Float16)(CF * im[k]);
            xr[k]  = im[k];
        }
        *reinterpret_cast<half8*>(xtp + i * S + j0) = imv;   // xt = img
    };
    loadC(t0, wh0, wv0, ci0, x0);
    loadC(t1, wh1, wv1, ci1, x1);
    if (act2) loadC(t2, wh2, wv2, ci2, x2);
    yh0 = splat8(0.f); yh1 = splat8(0.f); yh2 = splat8(0.f);
    yv0 = splat8(0.f); yv1 = splat8(0.f); yv2 = splat8(0.f);
    if (tid == 0) yhe[0] = (_Float16)0.0f;   // left edge of chunk 0 (outside -> 0)
    __syncthreads();

    for (int it = 0; it < 20; ++it) {
        // -------- dual: y = clamp(y + grad(xt) * (SIGMA*w)) --------
        auto dualC = [&](int t, int base, half8 wh, half8 wv, half8& yh, half8& yv) {
            half8 cv = *reinterpret_cast<const half8*>(xtp + base);
            _Float16 rt = xtp[base + 8];
            half8 bv = *reinterpret_cast<const half8*>(xtp + base + S);
            half8 sh = __builtin_shufflevector(cv, cv, 1, 2, 3, 4, 5, 6, 7, 7);
            sh[7] = rt;
            yh = clamp8(yh + (sh - cv) * wh);
            yv = clamp8(yv + (bv - cv) * wv);
            *reinterpret_cast<half8*>(yvp + base) = yv;
            yhe[t + 1] = yh[7];
        };
        dualC(t0, b0, wh0, wv0, yh0, yv0);
        dualC(t1, b1, wh1, wv1, yh1, yv1);
        if (act2) dualC(t2, b2, wh2, wv2, yh2, yv2);
        __syncthreads();

        // -------- primal: x = x*INVD + TIV*div(y) + CF*img; xt = 1.5x - 0.5x_old --------
        auto primC = [&](int t, int base, half8 yh, half8 yv, half8 ci, float8& x) {
            _Float16 yl = yhe[t];
            half8 yva = *reinterpret_cast<const half8*>(yvp + base - S);
            half8 ysh = __builtin_shufflevector(yh, yh, 0, 0, 1, 2, 3, 4, 5, 6);
            ysh[0] = yl;
            half8 dv16 = (yh - ysh) + (yv - yva);
            half8 xth;
#pragma unroll
            for (int k = 0; k < 8; ++k) {
                float xo = x[k];
                float xn = fmaf(xo, INVD, fmaf(TIV, (float)dv16[k], (float)ci[k]));
                x[k] = xn;
                xth[k] = (_Float16)(1.5f * xn - 0.5f * xo);
            }
            *reinterpret_cast<half8*>(xtp + base) = xth;
        };
        primC(t0, b0, yh0, yv0, ci0, x0);
        primC(t1, b1, yh1, yv1, ci1, x1);
        if (act2) primC(t2, b2, yh2, yv2, ci2, x2);
        __syncthreads();
    }

    // ---------------- store center 64x64 as fp32 ----------------
    {
        const int r = tid >> 3;          // 0..63
        const int c = tid & 7;           // 0..7
        const int base = (HALO + r) * S + HALO + c * 8;   // 8B-aligned
        half4v a = *reinterpret_cast<const half4v*>(xtp + base);
        half4v b = *reinterpret_cast<const half4v*>(xtp + base + 4);
        float4 o0 = make_float4((float)a[0], (float)a[1], (float)a[2], (float)a[3]);
        float4 o1 = make_float4((float)b[0], (float)b[1], (float)b[2], (float)b[3]);
        const long g = (long)(blockIdx.y * TILE + r) * W + blockIdx.x * TILE + c * 8;
        *reinterpret_cast<float4*>(out + g)     = o0;
        *reinterpret_cast<float4*>(out + g + 4) = o1;
    }
}

extern "C" void kernel_launch(void* const* d_in, const int* in_sizes, int n_in,
                              void* d_out, int out_size, void* d_ws, size_t ws_size,
                              hipStream_t stream) {
    const float* img = (const float*)d_in[0];   // (1,H,W)
    const float* wg  = (const float*)d_in[1];   // (2,H,W)
    float* out = (float*)d_out;

    dim3 grid(W / TILE, H / TILE);              // 64 x 64 = 4096 blocks
    fused_pd<<<grid, dim3(NT), 0, stream>>>(img, wg, out);
}

// Round 7
// 698.395 us; speedup vs baseline: 4.3336x; 1.0308x over previous
//
#include <hip/hip_runtime.h>

static constexpr int H = 4096;
static constexpr int W = 4096;
static constexpr long N = (long)H * W;

static constexpr int TILE = 64;
static constexpr int HALO = 20;              // one per iteration per side
static constexpr int R    = TILE + 2*HALO;   // 104 region
static constexpr int S    = R;               // row stride (halfs)
static constexpr int PS   = R * S;           // plane size (halfs)
static constexpr int NCH  = R * (R/8);       // 1352 half8-chunk tasks
static constexpr int NT   = 704;             // 11 waves; 2 chunks/thread max

static constexpr float SIGMA = 14.285714285714286f;  // 1/(7*0.01)
static constexpr float INVD  = 1.0f / 1.07f;
static constexpr float TIV   = 0.01f / 1.07f;        // TAU/(1+LT)
static constexpr float CF    = 0.07f / 1.07f;        // LAMBDA*TAU/(1+LT)

typedef _Float16 half8  __attribute__((ext_vector_type(8)));
typedef _Float16 half4v __attribute__((ext_vector_type(4)));

__device__ __forceinline__ half8 splat8(float f) {
    _Float16 h = (_Float16)f;
    half8 v = {h, h, h, h, h, h, h, h};
    return v;
}
__device__ __forceinline__ half8 clamp8(half8 v) {
    v = __builtin_elementwise_min(v, splat8(1.0f));
    v = __builtin_elementwise_max(v, splat8(-1.0f));
    return v;
}

// All 20 iterations fused. LDS: xt plane, yv plane, compact yh-edge array.
// Thread-private state (sigma*w, CF*img, x fp16, own yh/yv) in registers:
// 2 chunks/thread x ~24 VGPR -> under the 64-VGPR occupancy cliff.
// BCs data-encoded (w=0 outside image / last col / last row); halo pixels
// invalidate 1/side/iter, HALO=20 covers 20 iterations; all out-of-range
// halo reads land on finite always-written LDS and feed only cone-invalid
// pixels (validated rounds 4-6).
__global__ __launch_bounds__(NT, 8) void fused_pd(
    const float* __restrict__ img,
    const float* __restrict__ wg,    // (2,H,W): wg[0]=w_h, wg[N]=w_v
    float* __restrict__ out)
{
    __shared__ _Float16 lds_s[2 * PS + NCH + 2];   // 45,972 B -> 2-3 blocks/CU
    _Float16* __restrict__ xtp = lds_s;            // x_tilde plane
    _Float16* __restrict__ yvp = lds_s + PS;       // y vertical plane
    _Float16* __restrict__ yhe = lds_s + 2 * PS;   // yh edges: yhe[t+1] = yh[7] of chunk t

    const int tid = threadIdx.x;
    const int gi0 = blockIdx.y * TILE - HALO;
    const int gj0 = blockIdx.x * TILE - HALO;
    const bool interior = (gi0 >= 0) && (gj0 >= 0) && (gi0 + R <= H) && (gj0 + R <= W);

    const int t0 = tid, t1 = tid + NT;
    const int i0_ = t0 / 13, i1_ = t1 / 13;
    const int b0 = i0_ * S + (t0 - i0_ * 13) * 8;
    const int b1 = i1_ * S + (t1 - i1_ * 13) * 8;
    const bool act1 = (t1 < NCH);

    // persistent per-chunk register state
    half8 wh0, wh1, wv0, wv1;   // SIGMA*w
    half8 ci0, ci1;             // CF*img
    half8 x0, x1;               // x (fp16 storage, fp32 arithmetic per iter)
    half8 yh0, yh1, yv0, yv1;   // dual state

    // ---------------- load & init ----------------
    auto loadC = [&](int t, half8& whr, half8& wvr, half8& cir, half8& xr) {
        const int i  = t / 13;
        const int j0 = (t - i * 13) * 8;
        const int gi = gi0 + i;
        const int gj = gj0 + j0;
        float im[8], wh[8], wv[8];
        if (interior) {
            const float4* ip = reinterpret_cast<const float4*>(img + (long)gi * W + gj);
            float4 a = ip[0], b = ip[1];
            im[0]=a.x; im[1]=a.y; im[2]=a.z; im[3]=a.w;
            im[4]=b.x; im[5]=b.y; im[6]=b.z; im[7]=b.w;
            const float4* hp = reinterpret_cast<const float4*>(wg + (long)gi * W + gj);
            float4 c = hp[0], d = hp[1];
            wh[0]=c.x*SIGMA; wh[1]=c.y*SIGMA; wh[2]=c.z*SIGMA; wh[3]=c.w*SIGMA;
            wh[4]=d.x*SIGMA; wh[5]=d.y*SIGMA; wh[6]=d.z*SIGMA; wh[7]=d.w*SIGMA;
            const float4* vp = reinterpret_cast<const float4*>(wg + N + (long)gi * W + gj);
            float4 e = vp[0], f = vp[1];
            wv[0]=e.x*SIGMA; wv[1]=e.y*SIGMA; wv[2]=e.z*SIGMA; wv[3]=e.w*SIGMA;
            wv[4]=f.x*SIGMA; wv[5]=f.y*SIGMA; wv[6]=f.z*SIGMA; wv[7]=f.w*SIGMA;
        } else {
            const int gic = min(max(gi, 0), H - 1);
            const bool rowin = (gi >= 0) && (gi < H);
#pragma unroll
            for (int k = 0; k < 8; ++k) {
                const int gjk = gj + k;
                const int gjc = min(max(gjk, 0), W - 1);
                const bool inim = rowin && (gjk >= 0) && (gjk < W);
                const long o = (long)gic * W + gjc;
                im[k] = img[o];
                wh[k] = (inim && gjk < W - 1) ? SIGMA * wg[o]     : 0.0f;
                wv[k] = (inim && gi  < H - 1) ? SIGMA * wg[N + o] : 0.0f;
            }
        }
        half8 imv;
#pragma unroll
        for (int k = 0; k < 8; ++k) {
            imv[k] = (_Float16)im[k];
            whr[k] = (_Float16)wh[k];
            wvr[k] = (_Float16)wv[k];
            cir[k] = (_Float16)(CF * im[k]);
        }
        xr = imv;
        *reinterpret_cast<half8*>(xtp + i * S + j0) = imv;   // xt = img
    };
    loadC(t0, wh0, wv0, ci0, x0);
    if (act1) loadC(t1, wh1, wv1, ci1, x1);
    yh0 = splat8(0.f); yh1 = splat8(0.f);
    yv0 = splat8(0.f); yv1 = splat8(0.f);
    if (tid == 0) yhe[0] = (_Float16)0.0f;   // left edge of chunk 0
    __syncthreads();

    for (int it = 0; it < 20; ++it) {
        // -------- dual: y = clamp(y + grad(xt) * (SIGMA*w)) --------
        auto dualC = [&](int t, int base, half8 wh, half8 wv, half8& yh, half8& yv) {
            half8 cv = *reinterpret_cast<const half8*>(xtp + base);
            _Float16 rt = xtp[base + 8];
            half8 bv = *reinterpret_cast<const half8*>(xtp + base + S);
            half8 sh = __builtin_shufflevector(cv, cv, 1, 2, 3, 4, 5, 6, 7, 7);
            sh[7] = rt;
            yh = clamp8(yh + (sh - cv) * wh);
            yv = clamp8(yv + (bv - cv) * wv);
            *reinterpret_cast<half8*>(yvp + base) = yv;
            yhe[t + 1] = yh[7];
        };
        dualC(t0, b0, wh0, wv0, yh0, yv0);
        if (act1) dualC(t1, b1, wh1, wv1, yh1, yv1);
        __syncthreads();

        // -------- primal: x = x*INVD + TIV*div(y) + CF*img; xt = 1.5x - 0.5x_old --------
        auto primC = [&](int t, int base, half8 yh, half8 yv, half8 ci, half8& x) {
            _Float16 yl = yhe[t];
            half8 yva = *reinterpret_cast<const half8*>(yvp + base - S);
            half8 ysh = __builtin_shufflevector(yh, yh, 0, 0, 1, 2, 3, 4, 5, 6);
            ysh[0] = yl;
            half8 dv16 = (yh - ysh) + (yv - yva);
            half8 xth, xnh;
#pragma unroll
            for (int k = 0; k < 8; ++k) {
                float xo = (float)x[k];
                float xn = fmaf(xo, INVD, fmaf(TIV, (float)dv16[k], (float)ci[k]));
                xnh[k] = (_Float16)xn;
                xth[k] = (_Float16)(1.5f * xn - 0.5f * xo);
            }
            x = xnh;
            *reinterpret_cast<half8*>(xtp + base) = xth;
        };
        primC(t0, b0, yh0, yv0, ci0, x0);
        if (act1) primC(t1, b1, yh1, yv1, ci1, x1);
        __syncthreads();
    }

    // ---------------- store center 64x64 as fp32 ----------------
    if (tid < 512) {
        const int r = tid >> 3;          // 0..63
        const int c = tid & 7;           // 0..7
        const int base = (HALO + r) * S + HALO + c * 8;   // 8B-aligned
        half4v a = *reinterpret_cast<const half4v*>(xtp + base);
        half4v b = *reinterpret_cast<const half4v*>(xtp + base + 4);
        float4 o0 = make_float4((float)a[0], (float)a[1], (float)a[2], (float)a[3]);
        float4 o1 = make_float4((float)b[0], (float)b[1], (float)b[2], (float)b[3]);
        const long g = (long)(blockIdx.y * TILE + r) * W + blockIdx.x * TILE + c * 8;
        *reinterpret_cast<float4*>(out + g)     = o0;
        *reinterpret_cast<float4*>(out + g + 4) = o1;
    }
}

extern "C" void kernel_launch(void* const* d_in, const int* in_sizes, int n_in,
                              void* d_out, int out_size, void* d_ws, size_t ws_size,
                              hipStream_t stream) {
    const float* img = (const float*)d_in[0];   // (1,H,W)
    const float* wg  = (const float*)d_in[1];   // (2,H,W)
    float* out = (float*)d_out;

    dim3 grid(W / TILE, H / TILE);              // 64 x 64 = 4096 blocks
    fused_pd<<<grid, dim3(NT), 0, stream>>>(img, wg, out);
}

// Round 8
// 500.305 us; speedup vs baseline: 6.0494x; 1.3959x over previous
//
#include <hip/hip_runtime.h>

static constexpr int H = 4096;
static constexpr int W = 4096;
static constexpr long N = (long)H * W;

static constexpr int TILE = 64;
static constexpr int HALO = 20;              // one per iteration per side
static constexpr int R    = TILE + 2*HALO;   // 104 region
static constexpr int S    = R;               // row stride (halfs)
static constexpr int PS   = R * S;           // plane size (halfs)
static constexpr int NCH  = R * (R/8);       // 1352 half8-chunk tasks
static constexpr int NT   = 704;             // 11 waves; 2 chunks/thread max

static constexpr float SIGMA = 14.285714285714286f;  // 1/(7*0.01)
static constexpr float INVD  = 1.0f / 1.07f;
static constexpr float TIV   = 0.01f / 1.07f;        // TAU/(1+LT)
static constexpr float CF    = 0.07f / 1.07f;        // LAMBDA*TAU/(1+LT)

typedef _Float16 half8  __attribute__((ext_vector_type(8)));
typedef _Float16 half4v __attribute__((ext_vector_type(4)));

__device__ __forceinline__ half8 splat8(float f) {
    _Float16 h = (_Float16)f;
    half8 v = {h, h, h, h, h, h, h, h};
    return v;
}
__device__ __forceinline__ half8 clamp8(half8 v) {
    v = __builtin_elementwise_min(v, splat8(1.0f));
    v = __builtin_elementwise_max(v, splat8(-1.0f));
    return v;
}

// All 20 iterations fused. LDS: xt plane, yv plane, compact yh-edge array.
// Thread-private state (sigma*w, CF*img, x, own yh/yv) in fp16 registers;
// both dual AND primal math fully packed fp16 (v_pk_*). BCs data-encoded
// (w=0 outside image / last col / last row); halo pixels invalidate
// 1/side/iter, HALO=20 covers 20 iterations; out-of-range halo reads land
// on finite always-written LDS and feed only cone-invalid pixels
// (validated rounds 4-7).
__global__ __launch_bounds__(NT, 8) void fused_pd(
    const float* __restrict__ img,
    const float* __restrict__ wg,    // (2,H,W): wg[0]=w_h, wg[N]=w_v
    float* __restrict__ out)
{
    __shared__ _Float16 lds_s[2 * PS + NCH + 2];   // 45,972 B
    _Float16* __restrict__ xtp = lds_s;            // x_tilde plane
    _Float16* __restrict__ yvp = lds_s + PS;       // y vertical plane
    _Float16* __restrict__ yhe = lds_s + 2 * PS;   // yh edges: yhe[t+1] = yh[7] of chunk t

    const int tid = threadIdx.x;
    const int gi0 = blockIdx.y * TILE - HALO;
    const int gj0 = blockIdx.x * TILE - HALO;
    const bool interior = (gi0 >= 0) && (gj0 >= 0) && (gi0 + R <= H) && (gj0 + R <= W);

    const int t0 = tid, t1 = tid + NT;
    const int i0_ = t0 / 13, i1_ = t1 / 13;
    const int b0 = i0_ * S + (t0 - i0_ * 13) * 8;
    const int b1 = i1_ * S + (t1 - i1_ * 13) * 8;
    const bool act1 = (t1 < NCH);

    // packed loop constants (hoisted once)
    const half8 kTIV  = splat8(TIV);
    const half8 kINVD = splat8(INVD);
    const half8 k15   = splat8(1.5f);
    const half8 kM05  = splat8(-0.5f);

    // persistent per-chunk register state (all fp16)
    half8 wh0, wh1, wv0, wv1;   // SIGMA*w
    half8 ci0, ci1;             // CF*img
    half8 x0, x1;               // x
    half8 yh0, yh1, yv0, yv1;   // dual state

    // ---------------- load & init ----------------
    auto loadC = [&](int t, half8& whr, half8& wvr, half8& cir, half8& xr) {
        const int i  = t / 13;
        const int j0 = (t - i * 13) * 8;
        const int gi = gi0 + i;
        const int gj = gj0 + j0;
        float im[8], wh[8], wv[8];
        if (interior) {
            const float4* ip = reinterpret_cast<const float4*>(img + (long)gi * W + gj);
            float4 a = ip[0], b = ip[1];
            im[0]=a.x; im[1]=a.y; im[2]=a.z; im[3]=a.w;
            im[4]=b.x; im[5]=b.y; im[6]=b.z; im[7]=b.w;
            const float4* hp = reinterpret_cast<const float4*>(wg + (long)gi * W + gj);
            float4 c = hp[0], d = hp[1];
            wh[0]=c.x*SIGMA; wh[1]=c.y*SIGMA; wh[2]=c.z*SIGMA; wh[3]=c.w*SIGMA;
            wh[4]=d.x*SIGMA; wh[5]=d.y*SIGMA; wh[6]=d.z*SIGMA; wh[7]=d.w*SIGMA;
            const float4* vp = reinterpret_cast<const float4*>(wg + N + (long)gi * W + gj);
            float4 e = vp[0], f = vp[1];
            wv[0]=e.x*SIGMA; wv[1]=e.y*SIGMA; wv[2]=e.z*SIGMA; wv[3]=e.w*SIGMA;
            wv[4]=f.x*SIGMA; wv[5]=f.y*SIGMA; wv[6]=f.z*SIGMA; wv[7]=f.w*SIGMA;
        } else {
            const int gic = min(max(gi, 0), H - 1);
            const bool rowin = (gi >= 0) && (gi < H);
#pragma unroll
            for (int k = 0; k < 8; ++k) {
                const int gjk = gj + k;
                const int gjc = min(max(gjk, 0), W - 1);
                const bool inim = rowin && (gjk >= 0) && (gjk < W);
                const long o = (long)gic * W + gjc;
                im[k] = img[o];
                wh[k] = (inim && gjk < W - 1) ? SIGMA * wg[o]     : 0.0f;
                wv[k] = (inim && gi  < H - 1) ? SIGMA * wg[N + o] : 0.0f;
            }
        }
        half8 imv;
#pragma unroll
        for (int k = 0; k < 8; ++k) {
            imv[k] = (_Float16)im[k];
            whr[k] = (_Float16)wh[k];
            wvr[k] = (_Float16)wv[k];
            cir[k] = (_Float16)(CF * im[k]);
        }
        xr = imv;
        *reinterpret_cast<half8*>(xtp + i * S + j0) = imv;   // xt = img
    };
    loadC(t0, wh0, wv0, ci0, x0);
    if (act1) loadC(t1, wh1, wv1, ci1, x1);
    yh0 = splat8(0.f); yh1 = splat8(0.f);
    yv0 = splat8(0.f); yv1 = splat8(0.f);
    if (tid == 0) yhe[0] = (_Float16)0.0f;   // left edge of chunk 0
    __syncthreads();

    for (int it = 0; it < 20; ++it) {
        // -------- dual: y = clamp(y + grad(xt) * (SIGMA*w)), packed fp16 --------
        auto dualC = [&](int t, int base, half8 wh, half8 wv, half8& yh, half8& yv) {
            half8 cv = *reinterpret_cast<const half8*>(xtp + base);
            _Float16 rt = xtp[base + 8];
            half8 bv = *reinterpret_cast<const half8*>(xtp + base + S);
            half8 sh = __builtin_shufflevector(cv, cv, 1, 2, 3, 4, 5, 6, 7, 7);
            sh[7] = rt;
            yh = clamp8((sh - cv) * wh + yh);   // pk_fma
            yv = clamp8((bv - cv) * wv + yv);   // pk_fma
            *reinterpret_cast<half8*>(yvp + base) = yv;
            yhe[t + 1] = yh[7];
        };
        dualC(t0, b0, wh0, wv0, yh0, yv0);
        if (act1) dualC(t1, b1, wh1, wv1, yh1, yv1);
        __syncthreads();

        // -------- primal, packed fp16:
        //   xn = x*INVD + (TIV*dv + ci);  xt = 1.5*xn - 0.5*x --------
        auto primC = [&](int t, int base, half8 yh, half8 yv, half8 ci, half8& x) {
            _Float16 yl = yhe[t];
            half8 yva = *reinterpret_cast<const half8*>(yvp + base - S);
            half8 ysh = __builtin_shufflevector(yh, yh, 0, 0, 1, 2, 3, 4, 5, 6);
            ysh[0] = yl;
            half8 dv = (yh - ysh) + (yv - yva);
            half8 tt = dv * kTIV + ci;          // pk_fma
            half8 xn = x * kINVD + tt;          // pk_fma
            half8 xt = xn * k15 + x * kM05;     // pk_mul + pk_fma
            x = xn;
            *reinterpret_cast<half8*>(xtp + base) = xt;
        };
        primC(t0, b0, yh0, yv0, ci0, x0);
        if (act1) primC(t1, b1, yh1, yv1, ci1, x1);
        __syncthreads();
    }

    // ---------------- store center 64x64 as fp32 ----------------
    if (tid < 512) {
        const int r = tid >> 3;          // 0..63
        const int c = tid & 7;           // 0..7
        const int base = (HALO + r) * S + HALO + c * 8;   // 8B-aligned
        half4v a = *reinterpret_cast<const half4v*>(xtp + base);
        half4v b = *reinterpret_cast<const half4v*>(xtp + base + 4);
        float4 o0 = make_float4((float)a[0], (float)a[1], (float)a[2], (float)a[3]);
        float4 o1 = make_float4((float)b[0], (float)b[1], (float)b[2], (float)b[3]);
        const long g = (long)(blockIdx.y * TILE + r) * W + blockIdx.x * TILE + c * 8;
        *reinterpret_cast<float4*>(out + g)     = o0;
        *reinterpret_cast<float4*>(out + g + 4) = o1;
    }
}

extern "C" void kernel_launch(void* const* d_in, const int* in_sizes, int n_in,
                              void* d_out, int out_size, void* d_ws, size_t ws_size,
                              hipStream_t stream) {
    const float* img = (const float*)d_in[0];   // (1,H,W)
    const float* wg  = (const float*)d_in[1];   // (2,H,W)
    float* out = (float*)d_out;

    dim3 grid(W / TILE, H / TILE);              // 64 x 64 = 4096 blocks
    fused_pd<<<grid, dim3(NT), 0, stream>>>(img, wg, out);
}